// Round 2
// baseline (250.579 us; speedup 1.0000x reference)
//
#include <hip/hip_runtime.h>
#include <hip/hip_bf16.h>
#include <stdint.h>

// Problem constants (fixed by reference)
#define B_  4
#define N_  8192
#define M_  8192
#define D_  64
#define NT_ 64    // N_/128
#define INF_BITS 0x7F800000    // +inf float bits; all stored mins are full squared dists (>=0),
                               // so signed-int atomicMin == float min

typedef __attribute__((ext_vector_type(8))) short bhalf8;   // 8 bf16 (MFMA A/B frag)
typedef __attribute__((ext_vector_type(4))) float f32x4;    // MFMA C/D frag

// ---- workspace layout (bytes) ----
// Bp: bf16 B', K=64 (2 k-steps of 32), fragment-chunk order:
//   chunk(rb, ks=0..1, lane=q*16+c) = row (rb*16+c), k = ks*32 + q*8 .. +7,
//   at ((rb*2+ks)*64 + lane)*8 elems -> lane-contiguous 1KB loads.
// A-side is converted INLINE in the main kernel (registers, 8x mc-redundant, L2/L3-hot)
//   -> no Ap/nA buffers, no A prep pass.
// nB: exact fp32 col norms. rowglob/colglob: float-bit-pattern int mins (atomicMin).
// cnt: 256 row-group counters (b,nt) + 32 col-group counters (b,mc) for the
//   distributed in-kernel finalize (last-arriver reduces, atomicAdds into out).
static const size_t OFF_B   = 0;                                    // 4 MB
static const size_t OFF_NB  = (size_t)B_ * M_ * D_ * 2;             // 4,194,304
static const size_t OFF_RG  = OFF_NB + (size_t)B_ * M_ * 4;         // +128 KB
static const size_t OFF_CG  = OFF_RG + (size_t)B_ * N_ * 4;         // +128 KB (contiguous with RG)
static const size_t OFF_CNT = OFF_CG + (size_t)B_ * M_ * 4;         // 288 ints
// end: ~4.6 MB

__device__ __forceinline__ short bf16bits(float x) {
    union { __hip_bfloat16 h; unsigned short u; } cv;
    cv.h = __float2bfloat16(x);
    return (short)cv.u;
}
__device__ __forceinline__ float min3f(float a, float b, float c) {
    return fminf(fminf(a, b), c);   // -> v_min3_f32
}

// ---------------- prep (B side only): K=64 fragment layout + fp32 norms; init mins/counters/out ----------------
__global__ __launch_bounds__(256) void chamfer_prep_b(
        const float* __restrict__ f2,
        unsigned short* __restrict__ Bp, float* __restrict__ nB,
        int* __restrict__ minbuf, int* __restrict__ cnt, float* __restrict__ out) {
    const int tid = threadIdx.x;
    const int gid = blockIdx.x * 256 + tid;          // 512 blocks -> 131072 threads
    if (gid == 0) out[0] = 0.f;                      // finishers atomicAdd into this
    if (gid < 65536) minbuf[gid] = INF_BITS;         // rowglob(32K) + colglob(32K), contiguous
    if (gid < 288) cnt[gid] = 0;                     // group counters

    const int rb = gid >> 6;                         // 0..2047: B-side 16-row block
    const int lane = tid & 63;
    const int q = lane >> 4, c = lane & 15;

    const float* row = f2 + ((size_t)rb * 16 + c) * 64;
    f32x4 u0 = *(const f32x4*)(row + q * 8);
    f32x4 u1 = *(const f32x4*)(row + q * 8 + 4);
    f32x4 u2 = *(const f32x4*)(row + 32 + q * 8);
    f32x4 u3 = *(const f32x4*)(row + 32 + q * 8 + 4);

    float ss = 0.f;
    #pragma unroll
    for (int k = 0; k < 4; k++)
        ss += u0[k] * u0[k] + u1[k] * u1[k] + u2[k] * u2[k] + u3[k] * u3[k];
    ss += __shfl_xor(ss, 16, 64);
    ss += __shfl_xor(ss, 32, 64);                    // full ||col m||^2 in every lane (fp32, exact)

    bhalf8 o0, o1;
    #pragma unroll
    for (int k = 0; k < 4; k++) {
        o0[k]     = bf16bits(u0[k]);
        o0[4 + k] = bf16bits(u1[k]);
        o1[k]     = bf16bits(u2[k]);
        o1[4 + k] = bf16bits(u3[k]);
    }
    if (q == 0) nB[rb * 16 + c] = ss;
    *(bhalf8*)(Bp + ((size_t)(rb * 2 + 0) * 64 + lane) * 8) = o0;
    *(bhalf8*)(Bp + ((size_t)(rb * 2 + 1) * 64 + lane) * 8) = o1;
}

// ---------------- main: inline-A + K=64 wait-free loop + distributed finalize ----------------
// grid (mc=8, nt=64, b=4) = 2048 blocks; wave tile 64 rows x 32 cols/step, 16 steps.
// Inner loop identical to the round-1 kernel (isolates the plumbing change).
__global__ __launch_bounds__(256) void chamfer_main(
        const float* __restrict__ f, const unsigned short* __restrict__ Bp,
        const float* __restrict__ nB,
        int* __restrict__ rowglob, int* __restrict__ colglob,
        int* __restrict__ cnt, float* __restrict__ out) {
    const int mc = blockIdx.x;   // 0..7 : 8-tile mt chunk
    const int nt = blockIdx.y;   // 0..63
    const int b  = blockIdx.z;   // 0..3
    const int tid = threadIdx.x;
    const int wave = tid >> 6, lane = tid & 63;
    const int wr = wave >> 1, wc = wave & 1;
    const int q = lane >> 4, c = lane & 15;

    // q-slot col mins: stride 1064 words (1064%32==8 -> bank 8q+col: <=2-way, free)
    __shared__ int colmin[4][1064];   // [q][mtl*132 + col]
    __shared__ int rowmin[128];
    __shared__ float nyb[1024];       // this block's 1024 col norms (fp32)

    // stage col norms (4KB) + init min buffers
    *(f32x4*)&nyb[tid * 4] = *(const f32x4*)(nB + (size_t)b * 8192 + mc * 1024 + tid * 4);
    #pragma unroll
    for (int k = 0; k < 17; k++) {
        int idx = k * 256 + tid;
        if (idx < 4256) ((int*)colmin)[idx] = INF_BITS;
    }
    if (tid < 128) rowmin[tid] = INF_BITS;

    // ---- inline A conversion: rows nt*128 + wr*64 + i*16 + c straight from f ----
    // Bit-identical to the old prep path: same load pattern, bf16bits(u * -2), fp32 norms.
    const float* fa = f + ((size_t)b * 8192 + nt * 128 + wr * 64 + c) * 64 + q * 8;
    float ssv[4];
    bhalf8 af[4][2];
    #pragma unroll
    for (int i = 0; i < 4; i++) {
        const float* rp = fa + i * 1024;             // +16 rows
        f32x4 u0 = *(const f32x4*)(rp);
        f32x4 u1 = *(const f32x4*)(rp + 4);
        f32x4 u2 = *(const f32x4*)(rp + 32);
        f32x4 u3 = *(const f32x4*)(rp + 36);
        float ss = 0.f;
        #pragma unroll
        for (int k = 0; k < 4; k++)
            ss += u0[k] * u0[k] + u1[k] * u1[k] + u2[k] * u2[k] + u3[k] * u3[k];
        ss += __shfl_xor(ss, 16, 64);
        ss += __shfl_xor(ss, 32, 64);                // full ||row||^2 for (i, c) in every lane
        ssv[i] = ss;
        #pragma unroll
        for (int k = 0; k < 4; k++) {
            af[i][0][k]     = bf16bits(u0[k] * -2.0f);
            af[i][0][4 + k] = bf16bits(u1[k] * -2.0f);
            af[i][1][k]     = bf16bits(u2[k] * -2.0f);
            af[i][1][4 + k] = bf16bits(u3[k] * -2.0f);
        }
    }
    // C-init row norms: acc reg r of tile i is row i*16 + q*4 + r; norm lives in lane (q*4+r)
    f32x4 cnx[4];
    #pragma unroll
    for (int i = 0; i < 4; i++)
        #pragma unroll
        for (int r = 0; r < 4; r++)
            cnx[i][r] = __shfl(ssv[i], q * 4 + r, 64);

    __syncthreads();

    f32x4 rv[4];                 // running row-min, rows i*16+q*4+r
    #pragma unroll
    for (int i = 0; i < 4; i++) rv[i] = (f32x4){3.0e38f, 3.0e38f, 3.0e38f, 3.0e38f};

    // step s: mt = mc*8 + s/2, rbB = b*512 + mt*8 + wc*4 + (s&1)*2; cols = wc*64+(s&1)*32+jj*16+c
    const unsigned short* pE = Bp + (size_t)(b * 512 + mc * 64 + wc * 4) * 1024 + lane * 8;
    const unsigned short* pO = pE + 2048;

    auto loadB = [&](const unsigned short* p, bhalf8 (&bf)[2][2]) {
        #pragma unroll
        for (int jj = 0; jj < 2; jj++)
            #pragma unroll
            for (int ks = 0; ks < 2; ks++)
                bf[jj][ks] = *(const bhalf8*)(p + jj * 1024 + ks * 512);
    };

    auto process = [&](int mtl, int half, bhalf8 (&bf)[2][2]) {
        f32x4 acc[4][2];
        #pragma unroll
        for (int i = 0; i < 4; i++)
            #pragma unroll
            for (int jj = 0; jj < 2; jj++)
                acc[i][jj] = __builtin_amdgcn_mfma_f32_16x16x32_bf16(af[i][0], bf[jj][0], cnx[i], 0, 0, 0);
        #pragma unroll
        for (int i = 0; i < 4; i++)
            #pragma unroll
            for (int jj = 0; jj < 2; jj++)
                acc[i][jj] = __builtin_amdgcn_mfma_f32_16x16x32_bf16(af[i][1], bf[jj][1], acc[i][jj], 0, 0, 0);

        const int cb = mtl * 128 + wc * 64 + half * 32 + c;
        const float ny0 = nyb[cb];
        const float ny1 = nyb[cb + 16];

        float sv[4][2][4];
        #pragma unroll
        for (int i = 0; i < 4; i++)
            #pragma unroll
            for (int r = 0; r < 4; r++) {
                sv[i][0][r] = acc[i][0][r] + ny0;
                sv[i][1][r] = acc[i][1][r] + ny1;
                rv[i][r] = min3f(sv[i][0][r], sv[i][1][r], rv[i][r]);
            }

        #pragma unroll
        for (int jj = 0; jj < 2; jj++) {
            float t0 = min3f(sv[0][jj][0], sv[0][jj][1], sv[0][jj][2]);
            float t1 = min3f(sv[0][jj][3], sv[1][jj][0], sv[1][jj][1]);
            float t2 = min3f(sv[1][jj][2], sv[1][jj][3], sv[2][jj][0]);
            float t3 = min3f(sv[2][jj][1], sv[2][jj][2], sv[2][jj][3]);
            float t4 = min3f(sv[3][jj][0], sv[3][jj][1], sv[3][jj][2]);
            float t  = fminf(min3f(t0, t1, t2), min3f(t3, t4, sv[3][jj][3]));
            atomicMin(&colmin[q][mtl * 132 + wc * 64 + half * 32 + jj * 16 + c], __float_as_int(t));
        }
    };

    bhalf8 bf0[2][2], bf1[2][2];
    loadB(pE, bf0);
    #pragma unroll 1
    for (int mtl = 0; mtl < 8; mtl++) {
        loadB(pO, bf1);
        process(mtl, 0, bf0);
        pE += 8192;
        if (mtl < 7) loadB(pE, bf0);
        process(mtl, 1, bf1);
        pO += 8192;
    }

    // flush register row-mins to LDS, then one global atomicMin per row / per col
    #pragma unroll
    for (int i = 0; i < 4; i++)
        #pragma unroll
        for (int r = 0; r < 4; r++)
            atomicMin(&rowmin[wr * 64 + i * 16 + q * 4 + r], __float_as_int(rv[i][r]));
    __syncthreads();

    if (tid < 128)
        atomicMin(&rowglob[(size_t)(b * 64 + nt) * 128 + tid], rowmin[tid]);
    #pragma unroll
    for (int k = 0; k < 4; k++) {
        const int idx = k * 256 + tid;       // 0..1023 = mtl*128 + col
        const int mtl = idx >> 7, col = idx & 127;
        int m = min(min(colmin[0][mtl * 132 + col], colmin[1][mtl * 132 + col]),
                    min(colmin[2][mtl * 132 + col], colmin[3][mtl * 132 + col]));
        atomicMin(&colglob[(size_t)(b * 64 + mc * 8 + mtl) * 128 + col], m);
    }

    // ---- distributed finalize: last arriver per group reduces and accumulates out ----
    __threadfence();                       // publish this block's atomics (release)
    __syncthreads();                       // all threads' atomics + fences done
    __shared__ int roleR, roleC;
    if (tid == 0) {
        roleR = (atomicAdd(&cnt[b * 64 + nt], 1) == 7);          // 8 mc-blocks per row group
        roleC = (atomicAdd(&cnt[256 + b * 8 + mc], 1) == 63);    // 64 nt-blocks per col group
    }
    __syncthreads();

    float contrib = 0.f;
    if (roleR && tid < 128)                // read back via atomic (coherent across XCD L2s)
        contrib += __int_as_float(atomicMin(&rowglob[(size_t)(b * 64 + nt) * 128 + tid],
                                            0x7FFFFFFF)) * (1.0f / 32768.f);   // 1/(B*N)
    if (roleC) {
        int* base = colglob + (size_t)(b * 64 + mc * 8) * 128;   // contiguous 1024 ints
        #pragma unroll
        for (int k = 0; k < 4; k++)
            contrib += __int_as_float(atomicMin(&base[k * 256 + tid],
                                                0x7FFFFFFF)) * (1.0f / 32768.f);  // 1/(B*M)
    }
    if (roleR | roleC) {                   // block-uniform branch: barriers are safe
        #pragma unroll
        for (int off = 32; off; off >>= 1) contrib += __shfl_xor(contrib, off, 64);
        __shared__ float wsum[4];
        if (lane == 0) wsum[wave] = contrib;
        __syncthreads();
        if (tid == 0) atomicAdd(out, wsum[0] + wsum[1] + wsum[2] + wsum[3]);
    }
}

extern "C" void kernel_launch(void* const* d_in, const int* in_sizes, int n_in,
                              void* d_out, int out_size, void* d_ws, size_t ws_size,
                              hipStream_t stream) {
    const float* f  = (const float*)d_in[0];
    const float* f2 = (const float*)d_in[1];
    char* ws = (char*)d_ws;
    unsigned short* Bp = (unsigned short*)(ws + OFF_B);
    float* nB    = (float*)(ws + OFF_NB);
    int* rowglob = (int*)(ws + OFF_RG);
    int* colglob = (int*)(ws + OFF_CG);
    int* cnt     = (int*)(ws + OFF_CNT);
    float* out   = (float*)d_out;

    // prep (B only): ~13 MB traffic; also inits rowglob/colglob/counters/out
    chamfer_prep_b<<<dim3(512), dim3(256), 0, stream>>>(f2, Bp, nB, rowglob, cnt, out);

    // main: tile + inline-A + distributed finalize (no third kernel)
    chamfer_main<<<dim3(8, NT_, B_), dim3(256), 0, stream>>>(f, Bp, nB, rowglob, colglob, cnt, out);
}

// Round 3
// 114.630 us; speedup vs baseline: 2.1860x; 2.1860x over previous
//
#include <hip/hip_runtime.h>
#include <hip/hip_bf16.h>
#include <stdint.h>

// Problem constants (fixed by reference)
#define B_  4
#define N_  8192
#define M_  8192
#define D_  64
#define NT_ 64    // N_/128
#define RBN ((B_ * N_) / 16)   // 2048 16-row blocks on A side
#define INF_BITS 0x7F800000    // +inf float bits; all stored mins are full squared dists (>=0),
                               // so signed-int atomicMin == float min

typedef __attribute__((ext_vector_type(8))) short bhalf8;   // 8 bf16 (MFMA A/B frag)
typedef __attribute__((ext_vector_type(4))) float f32x4;    // MFMA C/D frag

// ---- workspace layout (bytes) ----
// A'/B': bf16, K=64 (2 k-steps of 32). Fragment-chunk order:
//   chunk(rb, ks=0..1, lane=q*16+c) = row (rb*16+c), k = ks*32 + q*8 .. +7,
//   at ((rb*2+ks)*64 + lane)*8 elems -> lane-contiguous 1KB loads.
// nA/nB: exact fp32 ||row||^2 per point (row norms ride the MFMA C-operand;
//   col norms added in the process epilogue from a 4KB LDS broadcast table).
// rowglob/colglob: per-point global mins as float BIT PATTERNS (int), atomicMin-accumulated.
// NOTE: tile kernel's 2-ahead pipeline over-reads Bp by up to 2 steps at the very end
//   (b=3, mc=7): max byte touched = 4,209,406 < OFF_NB + |nB| = 4,325,376 -> stays in workspace.
static const size_t OFF_A  = 0;
static const size_t OFF_B  = (size_t)B_ * N_ * D_ * 2;                 // 4,194,304
static const size_t OFF_NA = OFF_B + (size_t)B_ * M_ * D_ * 2;         // 8,388,608
static const size_t OFF_NB = OFF_NA + (size_t)B_ * N_ * 4;             // +128 KB
static const size_t OFF_RG = OFF_NB + (size_t)B_ * M_ * 4;             // +128 KB
static const size_t OFF_CG = OFF_RG + (size_t)B_ * N_ * 4;             // +128 KB
// end: OFF_CG + 128 KB = 8,912,896

__device__ __forceinline__ short bf16bits(float x) {
    union { __hip_bfloat16 h; unsigned short u; } cv;
    cv.h = __float2bfloat16(x);
    return (short)cv.u;
}
__device__ __forceinline__ float min3f(float a, float b, float c) {
    return fminf(fminf(a, b), c);   // -> v_min3_f32
}

// ---------------- prep: K=64 fragment layout + fp32 norms; init global min buffers + out ----------------
__global__ __launch_bounds__(256) void chamfer_prep(
        const float* __restrict__ f, const float* __restrict__ f2,
        unsigned short* __restrict__ Ap, unsigned short* __restrict__ Bp,
        float* __restrict__ nA, float* __restrict__ nB,
        int* __restrict__ minbuf, float* __restrict__ out) {
    const int tid = threadIdx.x;
    const int gid = blockIdx.x * 256 + tid;
    if (gid == 0) out[0] = 0.f;                      // finalize atomicAdds into this
    if (gid < 65536) minbuf[gid] = INF_BITS;         // rowglob(32K ints) + colglob(32K ints)

    const int w = gid >> 6;                          // 16-row block id, 0..4095
    const int lane = tid & 63;
    const int q = lane >> 4, c = lane & 15;
    const bool isA = w < RBN;
    const int rb = isA ? w : w - RBN;
    const float* src = isA ? f : f2;
    unsigned short* dst = isA ? Ap : Bp;
    float* ndst = isA ? nA : nB;
    const float scale = isA ? -2.0f : 1.0f;          // fold the -2 into A; exact in bf16

    const float* row = src + ((size_t)rb * 16 + c) * 64;
    f32x4 u0 = *(const f32x4*)(row + q * 8);
    f32x4 u1 = *(const f32x4*)(row + q * 8 + 4);
    f32x4 u2 = *(const f32x4*)(row + 32 + q * 8);
    f32x4 u3 = *(const f32x4*)(row + 32 + q * 8 + 4);

    float ss = 0.f;
    #pragma unroll
    for (int k = 0; k < 4; k++)
        ss += u0[k] * u0[k] + u1[k] * u1[k] + u2[k] * u2[k] + u3[k] * u3[k];
    ss += __shfl_xor(ss, 16, 64);
    ss += __shfl_xor(ss, 32, 64);                    // full ||row c||^2 in every lane (fp32, exact)

    bhalf8 o0, o1;
    #pragma unroll
    for (int k = 0; k < 4; k++) {
        o0[k]     = bf16bits(u0[k] * scale);
        o0[4 + k] = bf16bits(u1[k] * scale);
        o1[k]     = bf16bits(u2[k] * scale);
        o1[4 + k] = bf16bits(u3[k] * scale);
    }
    if (q == 0) ndst[rb * 16 + c] = ss;              // 16 consecutive floats per wave
    *(bhalf8*)(dst + ((size_t)(rb * 2 + 0) * 64 + lane) * 8) = o0;
    *(bhalf8*)(dst + ((size_t)(rb * 2 + 1) * 64 + lane) * 8) = o1;
}

// ---------------- tile kernel: K=64 wait-free loop, 2-steps-ahead B prefetch ----------------
// grid (mc=8, nt=64, b=4) = 2048 blocks; wave tile 64 rows x 32 cols/step, 16 steps.
// ONLY change vs round-1: the B-fragment pipeline is 4 named register buffers with
// dependence distance 2 (load for step s issued 2 processes before use), so the
// compiler can keep ~720 cyc of MFMA+VALU between a load and its s_waitcnt instead of ~360.
__global__ __launch_bounds__(256) void chamfer_tile(
        const unsigned short* __restrict__ Ap, const unsigned short* __restrict__ Bp,
        const float* __restrict__ nA, const float* __restrict__ nB,
        int* __restrict__ rowglob, int* __restrict__ colglob) {
    const int mc = blockIdx.x;   // 0..7 : 8-tile mt chunk
    const int nt = blockIdx.y;   // 0..63
    const int b  = blockIdx.z;   // 0..3
    const int tid = threadIdx.x;
    const int wave = tid >> 6, lane = tid & 63;
    const int wr = wave >> 1, wc = wave & 1;
    const int q = lane >> 4, c = lane & 15;

    // q-slot col mins: stride 1064 words (1064%32==8 -> bank 8q+col: <=2-way, free)
    __shared__ int colmin[4][1064];   // [q][mtl*132 + col], col 0..127, mtl 0..7
    __shared__ int rowmin[128];
    __shared__ float nyb[1024];       // this block's 1024 col norms (fp32)

    // stage col norms (4KB) + init min buffers
    *(f32x4*)&nyb[tid * 4] = *(const f32x4*)(nB + (size_t)b * 8192 + mc * 1024 + tid * 4);
    #pragma unroll
    for (int k = 0; k < 17; k++) {
        int idx = k * 256 + tid;
        if (idx < 4256) ((int*)colmin)[idx] = INF_BITS;
    }
    if (tid < 128) rowmin[tid] = INF_BITS;
    __syncthreads();

    // A fragments: rows nt*128 + wr*64 + i*16 + c, 2 k-steps. Loaded once (coalesced 1KB).
    const int rbA0 = b * 512 + nt * 8 + wr * 4;
    bhalf8 af[4][2];
    #pragma unroll
    for (int i = 0; i < 4; i++)
        #pragma unroll
        for (int ks = 0; ks < 2; ks++)
            af[i][ks] = *(const bhalf8*)(Ap + ((size_t)((rbA0 + i) * 2 + ks) * 64 + lane) * 8);

    // C-init row norms: acc reg r of tile i is row i*16 + q*4 + r -> one f32x4 load per i
    f32x4 cnx[4];
    {
        const float* nrow = nA + (size_t)b * 8192 + nt * 128 + wr * 64 + q * 4;
        #pragma unroll
        for (int i = 0; i < 4; i++)
            cnx[i] = *(const f32x4*)(nrow + i * 16);
    }

    f32x4 rv[4];                 // running row-min, rows i*16+q*4+r (this wave's 64 rows)
    #pragma unroll
    for (int i = 0; i < 4; i++) rv[i] = (f32x4){3.0e38f, 3.0e38f, 3.0e38f, 3.0e38f};

    // step s (0..15): mt = mc*8 + (s>>1), rbB = b*512 + mt*8 + wc*4 + (s&1)*2;
    // cols = wc*64 + (s&1)*32 + jj*16 + c. Offsets in shorts; rb stride = 1024.
    const unsigned short* base = Bp + (size_t)(b * 512 + mc * 64 + wc * 4) * 1024 + lane * 8;
    auto bptr = [&](int s) { return base + ((s >> 1) * 8192 + (s & 1) * 2048); };

    auto loadB = [&](const unsigned short* p, bhalf8 (&bf)[2][2]) {
        #pragma unroll
        for (int jj = 0; jj < 2; jj++)
            #pragma unroll
            for (int ks = 0; ks < 2; ks++)
                bf[jj][ks] = *(const bhalf8*)(p + jj * 1024 + ks * 512);
    };

    auto process = [&](int mtl, int half, bhalf8 (&bf)[2][2]) {
        f32x4 acc[4][2];
        #pragma unroll
        for (int i = 0; i < 4; i++)
            #pragma unroll
            for (int jj = 0; jj < 2; jj++)
                acc[i][jj] = __builtin_amdgcn_mfma_f32_16x16x32_bf16(af[i][0], bf[jj][0], cnx[i], 0, 0, 0);
        #pragma unroll
        for (int i = 0; i < 4; i++)
            #pragma unroll
            for (int jj = 0; jj < 2; jj++)
                acc[i][jj] = __builtin_amdgcn_mfma_f32_16x16x32_bf16(af[i][1], bf[jj][1], acc[i][jj], 0, 0, 0);
        // acc[i][jj][r] = nx - 2x.y for (row ..., col (mc*8+mtl)*128 + wc*64 + half*32 + jj*16 + c)

        // col norms: per-lane scalars, 4-way same-address LDS broadcast (free)
        const int cb = mtl * 128 + wc * 64 + half * 32 + c;
        const float ny0 = nyb[cb];
        const float ny1 = nyb[cb + 16];

        // sv = full squared distance; row-min fused as min3(sv0, sv1, rv)
        float sv[4][2][4];
        #pragma unroll
        for (int i = 0; i < 4; i++)
            #pragma unroll
            for (int r = 0; r < 4; r++) {
                sv[i][0][r] = acc[i][0][r] + ny0;
                sv[i][1][r] = acc[i][1][r] + ny1;
                rv[i][r] = min3f(sv[i][0][r], sv[i][1][r], rv[i][r]);
            }

        // col-min over this lane's 16 rows: balanced min3 tree (8 ops), then 1 ds_min per jj
        #pragma unroll
        for (int jj = 0; jj < 2; jj++) {
            float t0 = min3f(sv[0][jj][0], sv[0][jj][1], sv[0][jj][2]);
            float t1 = min3f(sv[0][jj][3], sv[1][jj][0], sv[1][jj][1]);
            float t2 = min3f(sv[1][jj][2], sv[1][jj][3], sv[2][jj][0]);
            float t3 = min3f(sv[2][jj][1], sv[2][jj][2], sv[2][jj][3]);
            float t4 = min3f(sv[3][jj][0], sv[3][jj][1], sv[3][jj][2]);
            float t  = fminf(min3f(t0, t1, t2), min3f(t3, t4, sv[3][jj][3]));
            atomicMin(&colmin[q][mtl * 132 + wc * 64 + half * 32 + jj * 16 + c], __float_as_int(t));
        }
    };

    // ---- 4-buffer, 2-steps-ahead pipeline (all buffer names static; rule-#20 safe) ----
    bhalf8 Bf0[2][2], Bf1[2][2], Bf2[2][2], Bf3[2][2];
    loadB(bptr(0), Bf0);
    loadB(bptr(1), Bf1);
    #pragma unroll 1
    for (int sp = 0; sp < 4; sp++) {     // steps 4sp .. 4sp+3
        const int s = sp * 4;
        loadB(bptr(s + 2), Bf2);  process(s >> 1,       0, Bf0);
        loadB(bptr(s + 3), Bf3);  process(s >> 1,       1, Bf1);
        loadB(bptr(s + 4), Bf0);  process((s + 2) >> 1, 0, Bf2);   // sp==3: over-read (in-workspace)
        loadB(bptr(s + 5), Bf1);  process((s + 2) >> 1, 1, Bf3);   // sp==3: over-read (in-workspace)
    }

    // flush register row-mins to LDS, then one global atomicMin per row / per col
    #pragma unroll
    for (int i = 0; i < 4; i++)
        #pragma unroll
        for (int r = 0; r < 4; r++)
            atomicMin(&rowmin[wr * 64 + i * 16 + q * 4 + r], __float_as_int(rv[i][r]));
    __syncthreads();

    if (tid < 128)
        atomicMin(&rowglob[(size_t)(b * 64 + nt) * 128 + tid], rowmin[tid]);
    #pragma unroll
    for (int k = 0; k < 4; k++) {
        const int idx = k * 256 + tid;       // 0..1023 = mtl*128 + col
        const int mtl = idx >> 7, col = idx & 127;
        int m = min(min(colmin[0][mtl * 132 + col], colmin[1][mtl * 132 + col]),
                    min(colmin[2][mtl * 132 + col], colmin[3][mtl * 132 + col]));
        atomicMin(&colglob[(size_t)(b * 64 + mc * 8 + mtl) * 128 + col], m);
    }
}

// ---------------- finalize: mean of rowglob + colglob (256 KB total) ----------------
__global__ __launch_bounds__(256) void chamfer_finalize(
        const int* __restrict__ rowglob, const int* __restrict__ colglob,
        float* __restrict__ out) {
    const int gid = blockIdx.x * 256 + threadIdx.x;   // 64 blocks -> 16384 threads
    float s = 0.f;
    #pragma unroll
    for (int k = 0; k < 2; k++) {
        s += __int_as_float(rowglob[gid + k * 16384]) * (1.0f / ((float)B_ * (float)N_));
        s += __int_as_float(colglob[gid + k * 16384]) * (1.0f / ((float)B_ * (float)M_));
    }
    __shared__ float sb[256];
    const int tid = threadIdx.x;
    sb[tid] = s;
    __syncthreads();
    for (int st = 128; st > 0; st >>= 1) {
        if (tid < st) sb[tid] += sb[tid + st];
        __syncthreads();
    }
    if (tid == 0) atomicAdd(out, sb[0]);
}

extern "C" void kernel_launch(void* const* d_in, const int* in_sizes, int n_in,
                              void* d_out, int out_size, void* d_ws, size_t ws_size,
                              hipStream_t stream) {
    const float* f  = (const float*)d_in[0];
    const float* f2 = (const float*)d_in[1];
    char* ws = (char*)d_ws;
    unsigned short* Ap = (unsigned short*)(ws + OFF_A);
    unsigned short* Bp = (unsigned short*)(ws + OFF_B);
    float* nA    = (float*)(ws + OFF_NA);
    float* nB    = (float*)(ws + OFF_NB);
    int* rowglob = (int*)(ws + OFF_RG);
    int* colglob = (int*)(ws + OFF_CG);
    float* out   = (float*)d_out;

    // prep: K=64 fragment layout + fp32 norms; inits rowglob/colglob/out
    chamfer_prep<<<dim3(1024), dim3(256), 0, stream>>>(f, f2, Ap, Bp, nA, nB, rowglob, out);

    // main: 2048 blocks, 16-step loop, 2-steps-ahead register prefetch
    chamfer_tile<<<dim3(8, NT_, B_), dim3(256), 0, stream>>>(Ap, Bp, nA, nB, rowglob, colglob);

    // finalize: 256 KB read + block sums -> scalar
    chamfer_finalize<<<dim3(64), dim3(256), 0, stream>>>(rowglob, colglob, out);
}

// Round 4
// 113.885 us; speedup vs baseline: 2.2003x; 1.0065x over previous
//
#include <hip/hip_runtime.h>
#include <hip/hip_bf16.h>
#include <stdint.h>

// Problem constants (fixed by reference)
#define B_  4
#define N_  8192
#define M_  8192
#define D_  64
#define NT_ 64    // N_/128
#define RBN ((B_ * N_) / 16)   // 2048 16-row blocks on A side
#define INF_BITS 0x7F800000    // +inf float bits; all stored mins are full squared dists (>=0),
                               // so signed-int atomicMin == float min

typedef __attribute__((ext_vector_type(8))) short bhalf8;   // 8 bf16 (MFMA A/B frag)
typedef __attribute__((ext_vector_type(4))) float f32x4;    // MFMA C/D frag

// ---- workspace layout (bytes) ----
// A'/B': bf16, K=64 (2 k-steps of 32). Fragment-chunk order:
//   chunk(rb, ks=0..1, lane=q*16+c) = row (rb*16+c), k = ks*32 + q*8 .. +7,
//   at ((rb*2+ks)*64 + lane)*8 elems -> lane-contiguous 1KB loads.
// nA/nB: exact fp32 ||row||^2 per point (row norms ride the MFMA C-operand;
//   col norms added in the process epilogue from a 4KB LDS broadcast table).
// rowglob/colglob: per-point global mins as float BIT PATTERNS (int), atomicMin-accumulated.
// NOTE: tile kernel's 2-ahead pipeline over-reads Bp by up to 2 steps past the end
//   (b=3, mcp=3): max byte = OFF_B + ~4,211,700 -> lands in the nA region, inside workspace.
static const size_t OFF_A  = 0;
static const size_t OFF_B  = (size_t)B_ * N_ * D_ * 2;                 // 4,194,304
static const size_t OFF_NA = OFF_B + (size_t)B_ * M_ * D_ * 2;         // 8,388,608
static const size_t OFF_NB = OFF_NA + (size_t)B_ * N_ * 4;             // +128 KB
static const size_t OFF_RG = OFF_NB + (size_t)B_ * M_ * 4;             // +128 KB
static const size_t OFF_CG = OFF_RG + (size_t)B_ * N_ * 4;             // +128 KB
// end: OFF_CG + 128 KB = 8,912,896

__device__ __forceinline__ short bf16bits(float x) {
    union { __hip_bfloat16 h; unsigned short u; } cv;
    cv.h = __float2bfloat16(x);
    return (short)cv.u;
}
__device__ __forceinline__ float min3f(float a, float b, float c) {
    return fminf(fminf(a, b), c);   // -> v_min3_f32
}

// ---------------- prep: K=64 fragment layout + fp32 norms; init global min buffers + out ----------------
__global__ __launch_bounds__(256) void chamfer_prep(
        const float* __restrict__ f, const float* __restrict__ f2,
        unsigned short* __restrict__ Ap, unsigned short* __restrict__ Bp,
        float* __restrict__ nA, float* __restrict__ nB,
        int* __restrict__ minbuf, float* __restrict__ out) {
    const int tid = threadIdx.x;
    const int gid = blockIdx.x * 256 + tid;
    if (gid == 0) out[0] = 0.f;                      // finalize atomicAdds into this
    if (gid < 65536) minbuf[gid] = INF_BITS;         // rowglob(32K ints) + colglob(32K ints)

    const int w = gid >> 6;                          // 16-row block id, 0..4095
    const int lane = tid & 63;
    const int q = lane >> 4, c = lane & 15;
    const bool isA = w < RBN;
    const int rb = isA ? w : w - RBN;
    const float* src = isA ? f : f2;
    unsigned short* dst = isA ? Ap : Bp;
    float* ndst = isA ? nA : nB;
    const float scale = isA ? -2.0f : 1.0f;          // fold the -2 into A; exact in bf16

    const float* row = src + ((size_t)rb * 16 + c) * 64;
    f32x4 u0 = *(const f32x4*)(row + q * 8);
    f32x4 u1 = *(const f32x4*)(row + q * 8 + 4);
    f32x4 u2 = *(const f32x4*)(row + 32 + q * 8);
    f32x4 u3 = *(const f32x4*)(row + 32 + q * 8 + 4);

    float ss = 0.f;
    #pragma unroll
    for (int k = 0; k < 4; k++)
        ss += u0[k] * u0[k] + u1[k] * u1[k] + u2[k] * u2[k] + u3[k] * u3[k];
    ss += __shfl_xor(ss, 16, 64);
    ss += __shfl_xor(ss, 32, 64);                    // full ||row c||^2 in every lane (fp32, exact)

    bhalf8 o0, o1;
    #pragma unroll
    for (int k = 0; k < 4; k++) {
        o0[k]     = bf16bits(u0[k] * scale);
        o0[4 + k] = bf16bits(u1[k] * scale);
        o1[k]     = bf16bits(u2[k] * scale);
        o1[4 + k] = bf16bits(u3[k] * scale);
    }
    if (q == 0) ndst[rb * 16 + c] = ss;              // 16 consecutive floats per wave
    *(bhalf8*)(dst + ((size_t)(rb * 2 + 0) * 64 + lane) * 8) = o0;
    *(bhalf8*)(dst + ((size_t)(rb * 2 + 1) * 64 + lane) * 8) = o1;
}

// ---------------- tile kernel: merged mc-pairs, 32 steps, zero in-loop LDS atomics ----------------
// grid (mcp=4, nt=64, b=4) = 1024 blocks (fully co-resident at 4 blocks/CU); wave tile
// 64 rows x 32 cols/step. Distance-2 register prefetch (4 named buffers) as round-3.
// Col-min partials: one conflict-free ds_write_b64 per process into a write-once slot
// (no atomics, no init); per-chunk flush reduces 8 contributors/col -> 1 colglob atomicMin.
__global__ __launch_bounds__(256) void chamfer_tile(
        const unsigned short* __restrict__ Ap, const unsigned short* __restrict__ Bp,
        const float* __restrict__ nA, const float* __restrict__ nB,
        int* __restrict__ rowglob, int* __restrict__ colglob) {
    const int mcp = blockIdx.x;  // 0..3 : 16-tile (2048-col) chunk-pair
    const int nt = blockIdx.y;   // 0..63
    const int b  = blockIdx.z;   // 0..3
    const int tid = threadIdx.x;
    const int wave = tid >> 6, lane = tid & 63;
    const int wr = wave >> 1, wc = wave & 1;
    const int q = lane >> 4, c = lane & 15;

    // colstore: per-(step-in-chunk, wave) region of 64 lanes x 2 jj floats. Written once
    // per chunk (plain b64 stores, lane-contiguous -> conflict-free), reduced at flush.
    __shared__ float colstore[8192];  // 64 regions x 128 floats = 32 KB
    __shared__ int rowmin[128];
    __shared__ float nyb[1024];       // current chunk's 1024 col norms (fp32)

    // stage chunk-0 col norms (4KB) + init rowmin
    *(f32x4*)&nyb[tid * 4] = *(const f32x4*)(nB + (size_t)b * 8192 + mcp * 2048 + tid * 4);
    if (tid < 128) rowmin[tid] = INF_BITS;
    __syncthreads();

    // A fragments: rows nt*128 + wr*64 + i*16 + c, 2 k-steps. Loaded once (coalesced 1KB).
    const int rbA0 = b * 512 + nt * 8 + wr * 4;
    bhalf8 af[4][2];
    #pragma unroll
    for (int i = 0; i < 4; i++)
        #pragma unroll
        for (int ks = 0; ks < 2; ks++)
            af[i][ks] = *(const bhalf8*)(Ap + ((size_t)((rbA0 + i) * 2 + ks) * 64 + lane) * 8);

    // C-init row norms: acc reg r of tile i is row i*16 + q*4 + r -> one f32x4 load per i
    f32x4 cnx[4];
    {
        const float* nrow = nA + (size_t)b * 8192 + nt * 128 + wr * 64 + q * 4;
        #pragma unroll
        for (int i = 0; i < 4; i++)
            cnx[i] = *(const f32x4*)(nrow + i * 16);
    }

    f32x4 rv[4];                 // running row-min over all 2048 cols, rows i*16+q*4+r
    #pragma unroll
    for (int i = 0; i < 4; i++) rv[i] = (f32x4){3.0e38f, 3.0e38f, 3.0e38f, 3.0e38f};

    // step s (0..31): chunk cc = s>>4, mtl = (s>>1)&7, half = s&1;
    // rbB = b*512 + mcp*128 + cc*64 + mtl*8 + wc*4 + half*2  -> offset = (s>>1)*8192 + (s&1)*2048 shorts.
    const unsigned short* base = Bp + (size_t)(b * 512 + mcp * 128 + wc * 4) * 1024 + lane * 8;
    auto bptr = [&](int s) { return base + ((s >> 1) * 8192 + (s & 1) * 2048); };

    auto loadB = [&](const unsigned short* p, bhalf8 (&bf)[2][2]) {
        #pragma unroll
        for (int jj = 0; jj < 2; jj++)
            #pragma unroll
            for (int ks = 0; ks < 2; ks++)
                bf[jj][ks] = *(const bhalf8*)(p + jj * 1024 + ks * 512);
    };

    // stl = step-in-chunk 0..15 (mtl = stl>>1, half = stl&1)
    auto process = [&](int stl, bhalf8 (&bf)[2][2]) {
        const int cb = (stl >> 1) * 128 + wc * 64 + (stl & 1) * 32 + c;
        const float ny0 = nyb[cb];          // 4-way same-address broadcast, conflict-free
        const float ny1 = nyb[cb + 16];

        f32x4 acc[4][2];
        #pragma unroll
        for (int i = 0; i < 4; i++)
            #pragma unroll
            for (int jj = 0; jj < 2; jj++)
                acc[i][jj] = __builtin_amdgcn_mfma_f32_16x16x32_bf16(af[i][0], bf[jj][0], cnx[i], 0, 0, 0);
        #pragma unroll
        for (int i = 0; i < 4; i++)
            #pragma unroll
            for (int jj = 0; jj < 2; jj++)
                acc[i][jj] = __builtin_amdgcn_mfma_f32_16x16x32_bf16(af[i][1], bf[jj][1], acc[i][jj], 0, 0, 0);

        // sv = full squared distance; row-min fused as min3(sv0, sv1, rv)
        float sv[4][2][4];
        #pragma unroll
        for (int i = 0; i < 4; i++)
            #pragma unroll
            for (int r = 0; r < 4; r++) {
                sv[i][0][r] = acc[i][0][r] + ny0;
                sv[i][1][r] = acc[i][1][r] + ny1;
                rv[i][r] = min3f(sv[i][0][r], sv[i][1][r], rv[i][r]);
            }

        // col-min over this lane's 16 rows: balanced min3 tree, then ONE ds_write_b64
        float t[2];
        #pragma unroll
        for (int jj = 0; jj < 2; jj++) {
            float t0 = min3f(sv[0][jj][0], sv[0][jj][1], sv[0][jj][2]);
            float t1 = min3f(sv[0][jj][3], sv[1][jj][0], sv[1][jj][1]);
            float t2 = min3f(sv[1][jj][2], sv[1][jj][3], sv[2][jj][0]);
            float t3 = min3f(sv[2][jj][1], sv[2][jj][2], sv[2][jj][3]);
            float t4 = min3f(sv[3][jj][0], sv[3][jj][1], sv[3][jj][2]);
            t[jj] = fminf(min3f(t0, t1, t2), min3f(t3, t4, sv[3][jj][3]));
        }
        *(float2*)&colstore[((stl * 4 + wave) * 64 + lane) * 2] = make_float2(t[0], t[1]);
    };

    // flush one chunk's colstore -> colglob; reload nyb for chunk 1
    auto chunkflush = [&](int cc) {
        __syncthreads();                              // all colstore writes visible
        #pragma unroll
        for (int k = 0; k < 4; k++) {
            const int col = k * 256 + tid;            // 0..1023 in-chunk col
            const int mtl = col >> 7, rem = col & 127;
            const int wcx = (rem >> 6) & 1, hf = (rem >> 5) & 1;
            const int jf = (rem >> 4) & 1, cx = rem & 15;
            const int sl = mtl * 2 + hf;
            float m = __int_as_float(INF_BITS);
            #pragma unroll
            for (int wrx = 0; wrx < 2; wrx++) {       // 8 contributors: q x wr
                const int fb = (sl * 4 + wrx * 2 + wcx) * 128 + cx * 2 + jf;
                float m0 = fminf(colstore[fb], colstore[fb + 32]);
                float m1 = fminf(colstore[fb + 64], colstore[fb + 96]);
                m = fminf(m, fminf(m0, m1));
            }
            atomicMin(&colglob[(size_t)b * 8192 + mcp * 2048 + cc * 1024 + col],
                      __float_as_int(m));
        }
        if (cc == 0)
            *(f32x4*)&nyb[tid * 4] =
                *(const f32x4*)(nB + (size_t)b * 8192 + mcp * 2048 + 1024 + tid * 4);
        __syncthreads();                              // nyb ready; colstore reusable
    };

    // ---- 4-buffer, distance-2 pipeline over 32 steps (buffer names static; rule-#20 safe) ----
    bhalf8 Bf0[2][2], Bf1[2][2], Bf2[2][2], Bf3[2][2];
    loadB(bptr(0), Bf0);
    loadB(bptr(1), Bf1);
    #pragma unroll 1
    for (int sp = 0; sp < 8; sp++) {     // steps 4sp .. 4sp+3
        if (sp == 4) chunkflush(0);      // block-uniform; chunk-1 loads already in flight
        const int s = sp * 4;
        const int sl = s & 15;
        loadB(bptr(s + 2), Bf2);  process(sl,     Bf0);
        loadB(bptr(s + 3), Bf3);  process(sl + 1, Bf1);
        loadB(bptr(s + 4), Bf0);  process(sl + 2, Bf2);   // sp==7: over-read (in-workspace)
        loadB(bptr(s + 5), Bf1);  process(sl + 3, Bf3);   // sp==7: over-read (in-workspace)
    }
    chunkflush(1);

    // flush register row-mins to LDS, then one global atomicMin per row
    #pragma unroll
    for (int i = 0; i < 4; i++)
        #pragma unroll
        for (int r = 0; r < 4; r++)
            atomicMin(&rowmin[wr * 64 + i * 16 + q * 4 + r], __float_as_int(rv[i][r]));
    __syncthreads();
    if (tid < 128)
        atomicMin(&rowglob[(size_t)(b * 64 + nt) * 128 + tid], rowmin[tid]);
}

// ---------------- finalize: mean of rowglob + colglob (256 KB total) ----------------
__global__ __launch_bounds__(256) void chamfer_finalize(
        const int* __restrict__ rowglob, const int* __restrict__ colglob,
        float* __restrict__ out) {
    const int gid = blockIdx.x * 256 + threadIdx.x;   // 64 blocks -> 16384 threads
    float s = 0.f;
    #pragma unroll
    for (int k = 0; k < 2; k++) {
        s += __int_as_float(rowglob[gid + k * 16384]) * (1.0f / ((float)B_ * (float)N_));
        s += __int_as_float(colglob[gid + k * 16384]) * (1.0f / ((float)B_ * (float)M_));
    }
    __shared__ float sb[256];
    const int tid = threadIdx.x;
    sb[tid] = s;
    __syncthreads();
    for (int st = 128; st > 0; st >>= 1) {
        if (tid < st) sb[tid] += sb[tid + st];
        __syncthreads();
    }
    if (tid == 0) atomicAdd(out, sb[0]);
}

extern "C" void kernel_launch(void* const* d_in, const int* in_sizes, int n_in,
                              void* d_out, int out_size, void* d_ws, size_t ws_size,
                              hipStream_t stream) {
    const float* f  = (const float*)d_in[0];
    const float* f2 = (const float*)d_in[1];
    char* ws = (char*)d_ws;
    unsigned short* Ap = (unsigned short*)(ws + OFF_A);
    unsigned short* Bp = (unsigned short*)(ws + OFF_B);
    float* nA    = (float*)(ws + OFF_NA);
    float* nB    = (float*)(ws + OFF_NB);
    int* rowglob = (int*)(ws + OFF_RG);
    int* colglob = (int*)(ws + OFF_CG);
    float* out   = (float*)d_out;

    // prep: K=64 fragment layout + fp32 norms; inits rowglob/colglob/out
    chamfer_prep<<<dim3(1024), dim3(256), 0, stream>>>(f, f2, Ap, Bp, nA, nB, rowglob, out);

    // main: 1024 co-resident blocks, 32-step loop, distance-2 prefetch, atomic-free inner loop
    chamfer_tile<<<dim3(4, NT_, B_), dim3(256), 0, stream>>>(Ap, Bp, nA, nB, rowglob, colglob);

    // finalize: 256 KB read + block sums -> scalar
    chamfer_finalize<<<dim3(64), dim3(256), 0, stream>>>(rowglob, colglob, out);
}